// Round 2
// baseline (1673.665 us; speedup 1.0000x reference)
//
#include <hip/hip_runtime.h>

#define TT 512   // sequence length
#define BB 64    // batch
#define HH 128   // hidden
#define G4 512   // 4*H

typedef short bf16x8 __attribute__((ext_vector_type(8)));
typedef float f32x4  __attribute__((ext_vector_type(4)));

__device__ __forceinline__ unsigned short f2bf(float x) {
    unsigned u = __float_as_uint(x);
    u += 0x7fff + ((u >> 16) & 1);           // RNE
    return (unsigned short)(u >> 16);
}
__device__ __forceinline__ float bf2f(unsigned short h) {
    return __uint_as_float(((unsigned)h) << 16);
}
__device__ __forceinline__ float sigf(float x) {
    float e = __builtin_amdgcn_exp2f(-1.4426950408889634f * x);
    return __builtin_amdgcn_rcpf(1.f + e);
}
__device__ __forceinline__ float tanh_(float x) {
    float e = __builtin_amdgcn_exp2f(2.8853900817779268f * x);   // e^(2x)
    return 1.f - 2.f * __builtin_amdgcn_rcpf(e + 1.f);
}

// ---------------- pre-GEMM (unchanged from R1, passing) ----------------
template<int K>
__global__ __launch_bounds__(256) void gemm_pre(
    const float* __restrict__ A, const float* __restrict__ W,
    const float* __restrict__ b0, const float* __restrict__ b1,
    float* __restrict__ C)
{
    __shared__ float As[8][132];
    __shared__ float Ws[8][132];
    const int bm = blockIdx.x * 128;
    const int bn = blockIdx.y * 128;
    const int tid = threadIdx.x;
    const int tx = tid & 15;
    const int ty = tid >> 4;
    const int lr = tid >> 1;
    const int lc = (tid & 1) * 4;

    float acc[8][8];
    #pragma unroll
    for (int i = 0; i < 8; ++i)
        #pragma unroll
        for (int j = 0; j < 8; ++j) acc[i][j] = 0.f;

    for (int k0 = 0; k0 < K; k0 += 8) {
        float4 av = *(const float4*)&A[(size_t)(bm + lr) * K + k0 + lc];
        float4 wv = *(const float4*)&W[(size_t)(bn + lr) * K + k0 + lc];
        __syncthreads();
        As[lc+0][lr] = av.x; As[lc+1][lr] = av.y; As[lc+2][lr] = av.z; As[lc+3][lr] = av.w;
        Ws[lc+0][lr] = wv.x; Ws[lc+1][lr] = wv.y; Ws[lc+2][lr] = wv.z; Ws[lc+3][lr] = wv.w;
        __syncthreads();
        #pragma unroll
        for (int kk = 0; kk < 8; ++kk) {
            float a[8], w[8];
            *(float4*)&a[0] = *(const float4*)&As[kk][ty*8];
            *(float4*)&a[4] = *(const float4*)&As[kk][ty*8+4];
            *(float4*)&w[0] = *(const float4*)&Ws[kk][tx*8];
            *(float4*)&w[4] = *(const float4*)&Ws[kk][tx*8+4];
            #pragma unroll
            for (int i = 0; i < 8; ++i)
                #pragma unroll
                for (int j = 0; j < 8; ++j)
                    acc[i][j] = fmaf(a[i], w[j], acc[i][j]);
        }
    }
    #pragma unroll
    for (int i = 0; i < 8; ++i) {
        int m = bm + ty*8 + i;
        #pragma unroll
        for (int j = 0; j < 8; j += 4) {
            int n = bn + tx*8 + j;
            float4 v;
            v.x = acc[i][j]   + b0[n]   + b1[n];
            v.y = acc[i][j+1] + b0[n+1] + b1[n+1];
            v.z = acc[i][j+2] + b0[n+2] + b1[n+2];
            v.w = acc[i][j+3] + b0[n+3] + b1[n+3];
            *(float4*)&C[(size_t)m * G4 + n] = v;
        }
    }
}

// ---------------- MFMA LSTM scan ----------------
// Grid: 8 blocks = 2 dir x 4 batch-groups of 16. Block: 512 thr (8 waves).
// Wave w owns gate n-tiles {cc*128 + 16w .. +16} for cc=0..3 (i,f,g,o of hidden
// j in [16w,16w+16)) -> each lane holds i,f,g,o for 4 (batch,j) cells in C regs.
// h staged in LDS [kc][16 rows=batch][32 cols=k] bf16, st_16x32 XOR swizzle,
// double-buffered; one barrier/step. w_hh hi/lo bf16 split for accuracy.
__global__ __launch_bounds__(512) void lstm_scan_mfma(
    const float* __restrict__ pre_f, const float* __restrict__ pre_b,
    const float* __restrict__ whh_f, const float* __restrict__ whh_b,
    float* __restrict__ out)
{
    const int dir = blockIdx.x >> 2;
    const int bg  = blockIdx.x & 3;
    const float* __restrict__ pre  = dir ? pre_b : pre_f;
    const float* __restrict__ w_hh = dir ? whh_b : whh_f;

    const int tid = threadIdx.x;
    const int w   = tid >> 6;      // wave 0..7
    const int l   = tid & 63;
    const int jl  = l & 15;
    const int rg  = l >> 4;        // 0..3
    const int j   = w * 16 + jl;   // hidden index of this lane's gate columns

    __shared__ unsigned short hbuf[2][4][512];   // [dbuf][kc][row*32 + swz(col)]

    // ---- load w_hh fragments (B operand), hi/lo bf16 split ----
    bf16x8 bHi[4][4], bLo[4][4];
    #pragma unroll
    for (int cc = 0; cc < 4; ++cc) {
        const float* wr = w_hh + (size_t)(cc * HH + j) * HH + rg * 8;
        #pragma unroll
        for (int kc = 0; kc < 4; ++kc) {
            const float* p = wr + kc * 32;
            bf16x8 fh, fl;
            #pragma unroll
            for (int q = 0; q < 8; ++q) {
                float v = p[q];
                unsigned short hi = f2bf(v);
                fh[q] = (short)hi;
                fl[q] = (short)f2bf(v - bf2f(hi));
            }
            bHi[cc][kc] = fh;
            bLo[cc][kc] = fl;
        }
    }

    // zero both h buffers (h0 = 0)
    for (int i = tid; i < 2 * 4 * 512; i += 512)
        ((unsigned short*)hbuf)[i] = 0;

    // ---- per-lane pre / out pointers (4 batch rows) ----
    const int b0 = bg * 16 + rg * 4;
    const int tau0 = dir ? (TT - 1) : 0;
    const float* pp[4];
    float* op[4];
    #pragma unroll
    for (int r = 0; r < 4; ++r) {
        pp[r] = pre + ((size_t)(b0 + r) * TT + tau0) * G4 + j;
        op[r] = out + ((size_t)(b0 + r) * TT + tau0) * (2 * HH) + dir * HH + j;
    }
    const int pstep = dir ? -G4 : G4;
    const int ostep = dir ? -(2 * HH) : (2 * HH);

    // first step's pre values (C-init layout: reg r = batch row rg*4+r)
    float pv[4][4];
    #pragma unroll
    for (int cc = 0; cc < 4; ++cc)
        #pragma unroll
        for (int r = 0; r < 4; ++r)
            pv[cc][r] = pp[r][cc * HH];

    // A-frag LDS read offset: row = jl, col base = rg*8, st_16x32 swizzle
    const int aoff = jl * 32 + ((rg * 8) ^ ((jl & 8) ? 16 : 0));
    const int kcw  = w >> 1;     // k-chunk this wave's h lands in
    const int jc   = j & 31;

    float cst[4] = {0.f, 0.f, 0.f, 0.f};

    __syncthreads();

    int cur = 0;
    for (int s = 0; s < TT; ++s) {
        // A fragments (shared across all 4 gate chunks)
        bf16x8 a[4];
        #pragma unroll
        for (int kc = 0; kc < 4; ++kc)
            a[kc] = *(const bf16x8*)&hbuf[cur][kc][aoff];

        f32x4 C[4];
        #pragma unroll
        for (int cc = 0; cc < 4; ++cc) {
            f32x4 acc;
            acc[0] = pv[cc][0]; acc[1] = pv[cc][1];
            acc[2] = pv[cc][2]; acc[3] = pv[cc][3];
            #pragma unroll
            for (int kc = 0; kc < 4; ++kc) {
                acc = __builtin_amdgcn_mfma_f32_16x16x32_bf16(a[kc], bHi[cc][kc], acc, 0, 0, 0);
                acc = __builtin_amdgcn_mfma_f32_16x16x32_bf16(a[kc], bLo[cc][kc], acc, 0, 0, 0);
            }
            C[cc] = acc;
        }

        // prefetch next step's pre (hidden under nonlinearity + barrier;
        // one-past-end reads stay inside d_ws — values unused)
        #pragma unroll
        for (int r = 0; r < 4; ++r) pp[r] += pstep;
        float pvn[4][4];
        #pragma unroll
        for (int cc = 0; cc < 4; ++cc)
            #pragma unroll
            for (int r = 0; r < 4; ++r)
                pvn[cc][r] = pp[r][cc * HH];

        // ---- cell update: all lanes, 4 cells each, fully in registers ----
        #pragma unroll
        for (int r = 0; r < 4; ++r) {
            float gi = C[0][r], gf = C[1][r], gg = C[2][r], go = C[3][r];
            float si = sigf(gi);
            float sf = sigf(gf);
            float so = sigf(go);
            float tg = tanh_(gg);
            float c  = sf * cst[r] + si * tg;
            cst[r] = c;
            float h = so * tanh_(c);
            op[r][0] = h;
            int bl = rg * 4 + r;
            hbuf[cur ^ 1][kcw][bl * 32 + (jc ^ ((bl & 8) ? 16 : 0))] = f2bf(h);
        }
        #pragma unroll
        for (int r = 0; r < 4; ++r) op[r] += ostep;

        __syncthreads();

        #pragma unroll
        for (int cc = 0; cc < 4; ++cc)
            #pragma unroll
            for (int r = 0; r < 4; ++r)
                pv[cc][r] = pvn[cc][r];
        cur ^= 1;
    }
}

// ---------------- FC (unchanged) ----------------
__global__ __launch_bounds__(256) void fc_kernel(
    const float* __restrict__ h2, const float* __restrict__ w_fc,
    const float* __restrict__ b_fc, float* __restrict__ out)
{
    int idx = blockIdx.x * 256 + threadIdx.x;
    int m = idx >> 6;
    int n = idx & 63;
    const float4* hr = (const float4*)(h2 + (size_t)m * 256);
    const float4* wr = (const float4*)(w_fc + (size_t)n * 256);
    float acc = 0.f;
    #pragma unroll 8
    for (int k = 0; k < 64; ++k) {
        float4 a = hr[k];
        float4 wv = wr[k];
        acc += a.x*wv.x + a.y*wv.y + a.z*wv.z + a.w*wv.w;
    }
    out[idx] = acc + b_fc[n];
}

extern "C" void kernel_launch(void* const* d_in, const int* in_sizes, int n_in,
                              void* d_out, int out_size, void* d_ws, size_t ws_size,
                              hipStream_t stream) {
    const float* x        = (const float*)d_in[0];
    const float* w_ih_l0  = (const float*)d_in[1];
    const float* w_hh_l0  = (const float*)d_in[2];
    const float* b_ih_l0  = (const float*)d_in[3];
    const float* b_hh_l0  = (const float*)d_in[4];
    const float* w_ih_l0r = (const float*)d_in[5];
    const float* w_hh_l0r = (const float*)d_in[6];
    const float* b_ih_l0r = (const float*)d_in[7];
    const float* b_hh_l0r = (const float*)d_in[8];
    const float* w_ih_l1  = (const float*)d_in[9];
    const float* w_hh_l1  = (const float*)d_in[10];
    const float* b_ih_l1  = (const float*)d_in[11];
    const float* b_hh_l1  = (const float*)d_in[12];
    const float* w_ih_l1r = (const float*)d_in[13];
    const float* w_hh_l1r = (const float*)d_in[14];
    const float* b_ih_l1r = (const float*)d_in[15];
    const float* b_hh_l1r = (const float*)d_in[16];
    const float* w_fc     = (const float*)d_in[17];
    const float* b_fc     = (const float*)d_in[18];

    float* ws    = (float*)d_ws;
    float* pre_f = ws;                       // 16,777,216 floats
    float* pre_b = ws + 16777216;            // 16,777,216 floats
    float* out0  = ws + 2 * 16777216;        // 8,388,608 floats
    float* out1  = out0 + 8388608;           // 8,388,608 floats

    dim3 gg(256, 4);

    // Layer 0
    gemm_pre<64><<<gg, 256, 0, stream>>>(x, w_ih_l0,  b_ih_l0,  b_hh_l0,  pre_f);
    gemm_pre<64><<<gg, 256, 0, stream>>>(x, w_ih_l0r, b_ih_l0r, b_hh_l0r, pre_b);
    lstm_scan_mfma<<<8, 512, 0, stream>>>(pre_f, pre_b, w_hh_l0, w_hh_l0r, out0);

    // Layer 1
    gemm_pre<256><<<gg, 256, 0, stream>>>(out0, w_ih_l1,  b_ih_l1,  b_hh_l1,  pre_f);
    gemm_pre<256><<<gg, 256, 0, stream>>>(out0, w_ih_l1r, b_ih_l1r, b_hh_l1r, pre_b);
    lstm_scan_mfma<<<8, 512, 0, stream>>>(pre_f, pre_b, w_hh_l1, w_hh_l1r, out1);

    // FC
    fc_kernel<<<(BB*TT*64)/256, 256, 0, stream>>>(out1, w_fc, b_fc, (float*)d_out);
}

// Round 3
// 1422.174 us; speedup vs baseline: 1.1768x; 1.1768x over previous
//
#include <hip/hip_runtime.h>

#define TT 512   // sequence length
#define BB 64    // batch
#define HH 128   // hidden
#define G4 512   // 4*H
#define PF 8     // prefetch depth (must divide TT)

// ---------------- pre-GEMM: C[m,g] = sum_k A[m,k]W[g,k] + b0[g] + b1[g] ----------------
// BK=64 staged in LDS; A:(M,K) rm, W:(512,K) rm, C:(M,512) rm. grid (M/128, 4), 256 thr.
template<int K>
__global__ __launch_bounds__(256) void gemm_pre(
    const float* __restrict__ A, const float* __restrict__ W,
    const float* __restrict__ b0, const float* __restrict__ b1,
    float* __restrict__ C)
{
    __shared__ float As[64][132];
    __shared__ float Ws[64][132];
    const int bm = blockIdx.x * 128;
    const int bn = blockIdx.y * 128;
    const int tid = threadIdx.x;
    const int tx = tid & 15;        // n micro
    const int ty = tid >> 4;        // m micro
    const int lr  = tid >> 1;       // staging row 0..127
    const int lc0 = (tid & 1) * 32; // staging col base

    float acc[8][8];
    #pragma unroll
    for (int i = 0; i < 8; ++i)
        #pragma unroll
        for (int j = 0; j < 8; ++j) acc[i][j] = 0.f;

    for (int k0 = 0; k0 < K; k0 += 64) {
        __syncthreads();
        #pragma unroll
        for (int q = 0; q < 8; ++q) {
            float4 av = *(const float4*)&A[(size_t)(bm + lr) * K + k0 + lc0 + q * 4];
            float4 wv = *(const float4*)&W[(size_t)(bn + lr) * K + k0 + lc0 + q * 4];
            As[lc0 + q*4 + 0][lr] = av.x; As[lc0 + q*4 + 1][lr] = av.y;
            As[lc0 + q*4 + 2][lr] = av.z; As[lc0 + q*4 + 3][lr] = av.w;
            Ws[lc0 + q*4 + 0][lr] = wv.x; Ws[lc0 + q*4 + 1][lr] = wv.y;
            Ws[lc0 + q*4 + 2][lr] = wv.z; Ws[lc0 + q*4 + 3][lr] = wv.w;
        }
        __syncthreads();
        #pragma unroll
        for (int kk = 0; kk < 64; ++kk) {
            float a[8], w[8];
            *(float4*)&a[0] = *(const float4*)&As[kk][ty*8];
            *(float4*)&a[4] = *(const float4*)&As[kk][ty*8+4];
            *(float4*)&w[0] = *(const float4*)&Ws[kk][tx*8];
            *(float4*)&w[4] = *(const float4*)&Ws[kk][tx*8+4];
            #pragma unroll
            for (int i = 0; i < 8; ++i)
                #pragma unroll
                for (int j = 0; j < 8; ++j)
                    acc[i][j] = fmaf(a[i], w[j], acc[i][j]);
        }
    }
    #pragma unroll
    for (int i = 0; i < 8; ++i) {
        int m = bm + ty*8 + i;
        #pragma unroll
        for (int j = 0; j < 8; j += 4) {
            int n = bn + tx*8 + j;
            float4 v;
            v.x = acc[i][j]   + b0[n]   + b1[n];
            v.y = acc[i][j+1] + b0[n+1] + b1[n+1];
            v.z = acc[i][j+2] + b0[n+2] + b1[n+2];
            v.w = acc[i][j+3] + b0[n+3] + b1[n+3];
            *(float4*)&C[(size_t)m * G4 + n] = v;
        }
    }
}

// ---------------- scalar LSTM scan, 128 blocks = 2dir x 64batch ----------------
// 512 thr; wave w, lane l: cell j = w*16 + (l&15), gate type tt = l>>4 (i,f,g,o).
// w_hh row pinned in 128 VGPRs. h double-buffered in LDS, 1 barrier/step.
// Nonlinearity distributed: each lane transforms its own gate; 3 shuffles gather
// a cell's f,g,o to the tt==0 lane, which owns c and writes h.
__global__ __launch_bounds__(512) void lstm_scan_v3(
    const float* __restrict__ pre_f, const float* __restrict__ pre_b,
    const float* __restrict__ whh_f, const float* __restrict__ whh_b,
    float* __restrict__ out)
{
    const int dir = blockIdx.x >> 6;
    const int b   = blockIdx.x & 63;
    const float* __restrict__ pre  = dir ? pre_b : pre_f;
    const float* __restrict__ w_hh = dir ? whh_b : whh_f;

    const int tid = threadIdx.x;
    const int w   = tid >> 6;
    const int l   = tid & 63;
    const int jl  = l & 15;
    const int tt  = l >> 4;          // gate type
    const int j   = w * 16 + jl;     // cell index 0..127
    const int g   = tt * HH + j;     // gate row 0..511

    __shared__ float h_lds[2][HH];

    // pin w_hh row g in VGPRs (all indices compile-time after unroll)
    float wv[HH];
    #pragma unroll
    for (int k = 0; k < HH; k += 4)
        *(float4*)&wv[k] = *(const float4*)&w_hh[(size_t)g * HH + k];

    if (tid < HH) { h_lds[0][tid] = 0.f; h_lds[1][tid] = 0.f; }

    const size_t base = (size_t)b * TT * G4 + g;
    float pf[PF];
    #pragma unroll
    for (int u = 0; u < PF; ++u) {
        int tau = dir ? (TT - 1 - u) : u;
        pf[u] = pre[base + (size_t)tau * G4];
    }

    float c = 0.f;
    const float ASIG = -1.4426950408889634f;  // -log2(e)
    const float ATAN =  2.8853900817779268f;  // 2*log2(e)
    const float aa = (tt == 2) ? ATAN : ASIG;

    __syncthreads();

    for (int s0 = 0; s0 < TT; s0 += PF) {
        #pragma unroll
        for (int u = 0; u < PF; ++u) {
            const int s = s0 + u;
            const int cur = u & 1;          // s0 even -> parity of s == parity of u
            const float* hb = h_lds[cur];

            float a0 = 0.f, a1 = 0.f, a2 = 0.f, a3 = 0.f;
            #pragma unroll
            for (int k = 0; k < HH; k += 4) {
                float4 h4 = *(const float4*)&hb[k];   // wave-uniform broadcast read
                a0 = fmaf(wv[k],   h4.x, a0);
                a1 = fmaf(wv[k+1], h4.y, a1);
                a2 = fmaf(wv[k+2], h4.z, a2);
                a3 = fmaf(wv[k+3], h4.w, a3);
            }
            float gate = pf[u] + ((a0 + a1) + (a2 + a3));

            // refill ring (clamped, branch-free; redundant tail loads are cache hits)
            {
                int sn = s + PF;
                int taun = dir ? (TT - 1 - sn) : sn;
                taun = taun < 0 ? 0 : (taun > TT - 1 ? TT - 1 : taun);
                pf[u] = pre[base + (size_t)taun * G4];
            }

            // transform own gate: sigmoid for i,f,o; tanh for g
            float e = __builtin_amdgcn_exp2f(aa * gate);
            float r = __builtin_amdgcn_rcpf(1.f + e);
            float v = (tt == 2) ? (1.f - 2.f * r) : r;

            // gather cell's sf, tg, so to the tt==0 lane
            float sf = __shfl(v, jl + 16);
            float tg = __shfl(v, jl + 32);
            float so = __shfl(v, jl + 48);

            if (tt == 0) {
                c = fmaf(sf, c, v * tg);
                float e2 = __builtin_amdgcn_exp2f(ATAN * c);
                float r2 = __builtin_amdgcn_rcpf(1.f + e2);
                float h = so * (1.f - 2.f * r2);
                h_lds[cur ^ 1][j] = h;
                int tau = dir ? (TT - 1 - s) : s;
                out[((size_t)b * TT + tau) * (2 * HH) + dir * HH + j] = h;
            }
            __syncthreads();
        }
    }
}

// ---------------- FC ----------------
__global__ __launch_bounds__(256) void fc_kernel(
    const float* __restrict__ h2, const float* __restrict__ w_fc,
    const float* __restrict__ b_fc, float* __restrict__ out)
{
    int idx = blockIdx.x * 256 + threadIdx.x;
    int m = idx >> 6;
    int n = idx & 63;
    const float4* hr = (const float4*)(h2 + (size_t)m * 256);
    const float4* wr = (const float4*)(w_fc + (size_t)n * 256);
    float acc = 0.f;
    #pragma unroll 8
    for (int k = 0; k < 64; ++k) {
        float4 a = hr[k];
        float4 wv = wr[k];
        acc += a.x*wv.x + a.y*wv.y + a.z*wv.z + a.w*wv.w;
    }
    out[idx] = acc + b_fc[n];
}

extern "C" void kernel_launch(void* const* d_in, const int* in_sizes, int n_in,
                              void* d_out, int out_size, void* d_ws, size_t ws_size,
                              hipStream_t stream) {
    const float* x        = (const float*)d_in[0];
    const float* w_ih_l0  = (const float*)d_in[1];
    const float* w_hh_l0  = (const float*)d_in[2];
    const float* b_ih_l0  = (const float*)d_in[3];
    const float* b_hh_l0  = (const float*)d_in[4];
    const float* w_ih_l0r = (const float*)d_in[5];
    const float* w_hh_l0r = (const float*)d_in[6];
    const float* b_ih_l0r = (const float*)d_in[7];
    const float* b_hh_l0r = (const float*)d_in[8];
    const float* w_ih_l1  = (const float*)d_in[9];
    const float* w_hh_l1  = (const float*)d_in[10];
    const float* b_ih_l1  = (const float*)d_in[11];
    const float* b_hh_l1  = (const float*)d_in[12];
    const float* w_ih_l1r = (const float*)d_in[13];
    const float* w_hh_l1r = (const float*)d_in[14];
    const float* b_ih_l1r = (const float*)d_in[15];
    const float* b_hh_l1r = (const float*)d_in[16];
    const float* w_fc     = (const float*)d_in[17];
    const float* b_fc     = (const float*)d_in[18];

    float* ws    = (float*)d_ws;
    float* pre_f = ws;                       // 16,777,216 floats
    float* pre_b = ws + 16777216;            // 16,777,216 floats
    float* out0  = ws + 2 * 16777216;        // 8,388,608 floats
    float* out1  = out0 + 8388608;           // 8,388,608 floats

    dim3 gg(256, 4);

    // Layer 0
    gemm_pre<64><<<gg, 256, 0, stream>>>(x, w_ih_l0,  b_ih_l0,  b_hh_l0,  pre_f);
    gemm_pre<64><<<gg, 256, 0, stream>>>(x, w_ih_l0r, b_ih_l0r, b_hh_l0r, pre_b);
    lstm_scan_v3<<<128, 512, 0, stream>>>(pre_f, pre_b, w_hh_l0, w_hh_l0r, out0);

    // Layer 1
    gemm_pre<256><<<gg, 256, 0, stream>>>(out0, w_ih_l1,  b_ih_l1,  b_hh_l1,  pre_f);
    gemm_pre<256><<<gg, 256, 0, stream>>>(out0, w_ih_l1r, b_ih_l1r, b_hh_l1r, pre_b);
    lstm_scan_v3<<<128, 512, 0, stream>>>(pre_f, pre_b, w_hh_l1, w_hh_l1r, out1);

    // FC
    fc_kernel<<<(BB*TT*64)/256, 256, 0, stream>>>(out1, w_fc, b_fc, (float*)d_out);
}